// Round 1
// baseline (1265.217 us; speedup 1.0000x reference)
//
#include <hip/hip_runtime.h>
#include <math.h>

#define LSEQ 624
#define NPG_C 1249
#define BATCH_C 64
#define NROWS (BATCH_C*LSEQ)          // 39936
#define N_NODES_C 79936
#define N_EDGES_C 639488
#define DIP 1160
#define DIN 512
#define CDIM 640
#define NH 8
#define HD 64
#define DS 64

// workspace layout (float offsets)
#define OFF_CHK   0            // 39936*16 = 638976
#define OFF_WF    638976       // 16*1160 = 18560
#define OFF_BF    657536       // 1160
#define OFF_WOP   658944       // 512*16 = 8192
#define OFF_BOP   667136       // 16
#define OFF_XBC   667392       // 39936*640 = 25559040
#define OFF_DTV   26226432     // 39936*8
#define OFF_DAV   26545920     // 39936*8
#define OFF_YS    26865408     // 39936*512 = 20447232
#define OFF_FEAT  47312640     // 79936*16 = 1278976
#define OFF_AGG   48591616     // 79936*128 = 10231808
// total 58823424 floats = 235.3 MB

__device__ __forceinline__ float siluf(float x) {
    return x / (1.f + __expf(-x));
}

// gather check-node rows: chk[row][k] = node_inputs[(row/624)*1249 + row%624][k]
__global__ void k_gather(const float* __restrict__ ni, float* __restrict__ chk) {
    int gid = blockIdx.x * 256 + threadIdx.x;
    if (gid >= NROWS * 16) return;
    int row = gid >> 4, k = gid & 15;
    int node = (row / LSEQ) * NPG_C + (row % LSEQ);
    chk[gid] = ni[node * 16 + k];
}

// fused weights: Wf = W_embed@W_in (16x1160), bf = b_embed@W_in + b_in
//                Wop = W_outp@W_proj (512x16), bop = b_outp@W_proj + b_proj
__global__ void k_fusew(const float* __restrict__ We, const float* __restrict__ be,
                        const float* __restrict__ Wi, const float* __restrict__ bi,
                        const float* __restrict__ Wo, const float* __restrict__ bo,
                        const float* __restrict__ Wp, const float* __restrict__ bp,
                        float* __restrict__ Wf, float* __restrict__ bf,
                        float* __restrict__ Wop, float* __restrict__ bop) {
    int id = blockIdx.x * 256 + threadIdx.x;
    if (id < 16 * DIP) {
        int i = id / DIP, j = id % DIP;
        float s = 0.f;
        for (int k = 0; k < 256; k++) s = fmaf(We[i * 256 + k], Wi[k * DIP + j], s);
        Wf[id] = s;
    } else if (id < 16 * DIP + DIP) {
        int j = id - 16 * DIP;
        float s = bi[j];
        for (int k = 0; k < 256; k++) s = fmaf(be[k], Wi[k * DIP + j], s);
        bf[j] = s;
    } else if (id < 16 * DIP + DIP + DIN * 16) {
        int id2 = id - (16 * DIP + DIP);
        int c = id2 >> 4, o = id2 & 15;
        float s = 0.f;
        for (int k = 0; k < 256; k++) s = fmaf(Wo[c * 256 + k], Wp[k * 16 + o], s);
        Wop[id2] = s;
    } else if (id < 16 * DIP + DIP + DIN * 16 + 16) {
        int o = id - (16 * DIP + DIP + DIN * 16);
        float s = bp[o];
        for (int k = 0; k < 256; k++) s = fmaf(bo[k], Wp[k * 16 + o], s);
        bop[o] = s;
    }
}

// fused in_proj(xBC cols) + causal depthwise conv + silu
// grid (2, 8, 64) block 320: c = bx*320+tid, t-chunk 78, b = bz
__global__ __launch_bounds__(320) void k_conv(const float* __restrict__ chk,
        const float* __restrict__ Wf, const float* __restrict__ bf,
        const float* __restrict__ cw, const float* __restrict__ cb,
        float* __restrict__ xBCc) {
    int c = blockIdx.x * 320 + threadIdx.x;     // 0..639
    int t0 = blockIdx.y * 78;
    int b = blockIdx.z;
    float w[16];
#pragma unroll
    for (int k = 0; k < 16; k++) w[k] = Wf[k * DIP + DIN + c];
    float bfx = bf[DIN + c];
    float k0 = cw[c * 4 + 0], k1 = cw[c * 4 + 1], k2 = cw[c * 4 + 2], k3 = cw[c * 4 + 3];
    float cbv = cb[c];
    const float* crow = chk + (size_t)(b * LSEQ) * 16;
    float* out = xBCc + (size_t)(b * LSEQ) * CDIM + c;

    float w0 = 0.f, w1 = 0.f, w2 = 0.f;
#pragma unroll
    for (int d = 3; d >= 1; d--) {
        int tau = t0 - d;
        float s = 0.f;
        if (tau >= 0) {
            s = bfx;
            const float* cr = crow + tau * 16;
#pragma unroll
            for (int k = 0; k < 16; k++) s = fmaf(cr[k], w[k], s);
        }
        if (d == 3) w0 = s; else if (d == 2) w1 = s; else w2 = s;
    }
    for (int t = t0; t < t0 + 78; t++) {
        const float* cr = crow + t * 16;
        float w3 = bfx;
#pragma unroll
        for (int k = 0; k < 16; k++) w3 = fmaf(cr[k], w[k], w3);
        float a = fmaf(k0, w0, fmaf(k1, w1, fmaf(k2, w2, fmaf(k3, w3, cbv))));
        out[(size_t)t * CDIM] = siluf(a);
        w0 = w1; w1 = w2; w2 = w3;
    }
}

// dt head columns: dt = softplus(chk@Wf_dt + bf_dt + dt_bias); dA = exp(-exp(A_log)*dt)
__global__ void k_dt(const float* __restrict__ chk, const float* __restrict__ Wf,
                     const float* __restrict__ bf, const float* __restrict__ A_log,
                     const float* __restrict__ dt_bias,
                     float* __restrict__ dtv, float* __restrict__ dAv) {
    int id = blockIdx.x * 256 + threadIdx.x;
    if (id >= NROWS * NH) return;
    int row = id >> 3, h = id & 7;
    const float* cr = chk + (size_t)row * 16;
    float s = bf[DIN + CDIM + h];
#pragma unroll
    for (int k = 0; k < 16; k++) s = fmaf(cr[k], Wf[k * DIP + DIN + CDIM + h], s);
    s += dt_bias[h];
    float sp = (s > 20.f) ? s : log1pf(__expf(s));
    dtv[id] = sp;
    dAv[id] = __expf(-__expf(A_log[h]) * sp);
}

// selective scan: one block per (head, b); 256 thr; thread owns p=tid>>2, n in [q*16,q*16+16)
__global__ __launch_bounds__(256) void k_scan(const float* __restrict__ xBCc,
        const float* __restrict__ dtv, const float* __restrict__ dAv,
        const float* __restrict__ Dskip, float* __restrict__ ys) {
    int head = blockIdx.x;
    int b = blockIdx.y;
    int tid = threadIdx.x;
    int p = tid >> 2, q = tid & 3;
    const float* xp  = xBCc + (size_t)(b * LSEQ) * CDIM + head * HD + p;
    const float* Bp  = xBCc + (size_t)(b * LSEQ) * CDIM + DIN + q * 16;
    const float* Cp  = Bp + DS;
    const float* dAp = dAv + (size_t)(b * LSEQ) * NH + head;
    const float* dtp = dtv + (size_t)(b * LSEQ) * NH + head;
    float* yp = ys + (size_t)(b * LSEQ) * DIN + head * HD + p;
    float dsk = Dskip[head];

    float h[16];
#pragma unroll
    for (int i = 0; i < 16; i++) h[i] = 0.f;

    for (int t = 0; t < LSEQ; t++) {
        size_t rb = (size_t)t * CDIM;
        float xv = xp[rb];
        float Bv[16], Cv[16];
        ((float4*)Bv)[0] = *(const float4*)(Bp + rb);
        ((float4*)Bv)[1] = *(const float4*)(Bp + rb + 4);
        ((float4*)Bv)[2] = *(const float4*)(Bp + rb + 8);
        ((float4*)Bv)[3] = *(const float4*)(Bp + rb + 12);
        ((float4*)Cv)[0] = *(const float4*)(Cp + rb);
        ((float4*)Cv)[1] = *(const float4*)(Cp + rb + 4);
        ((float4*)Cv)[2] = *(const float4*)(Cp + rb + 8);
        ((float4*)Cv)[3] = *(const float4*)(Cp + rb + 12);
        float a = dAp[(size_t)t * NH];
        float d = dtp[(size_t)t * NH];
        float dx = d * xv;
        float acc = 0.f;
#pragma unroll
        for (int i = 0; i < 16; i++) {
            h[i] = fmaf(a, h[i], dx * Bv[i]);
            acc = fmaf(h[i], Cv[i], acc);
        }
        acc += __shfl_xor(acc, 1);
        acc += __shfl_xor(acc, 2);
        if (q == 0) yp[(size_t)t * DIN] = fmaf(dsk, xv, acc);
    }
}

// gate (recompute z) + RMSNorm + fused out_proj@proj + scatter into feat
__global__ __launch_bounds__(256) void k_gate(const float* __restrict__ chk,
        const float* __restrict__ Wf, const float* __restrict__ bf,
        const float* __restrict__ ysb, const float* __restrict__ norm_w,
        const float* __restrict__ Wop, const float* __restrict__ bop,
        float* __restrict__ feat) {
    int row = blockIdx.x;
    int tid = threadIdx.x;
    int b = row / LSEQ, t = row % LSEQ;
    int node = b * NPG_C + t;
    __shared__ float sy[512];
    __shared__ float sred[256];
    __shared__ float swave[4];

    float cv[16];
    const float* cr = chk + (size_t)row * 16;
#pragma unroll
    for (int k = 0; k < 16; k++) cv[k] = cr[k];
    int c1 = tid, c2 = tid + 256;
    float z1 = bf[c1], z2 = bf[c2];
#pragma unroll
    for (int k = 0; k < 16; k++) {
        z1 = fmaf(cv[k], Wf[k * DIP + c1], z1);
        z2 = fmaf(cv[k], Wf[k * DIP + c2], z2);
    }
    float y1 = ysb[(size_t)row * DIN + c1] * siluf(z1);
    float y2 = ysb[(size_t)row * DIN + c2] * siluf(z2);
    float ss = y1 * y1 + y2 * y2;
#pragma unroll
    for (int off = 32; off >= 1; off >>= 1) ss += __shfl_xor(ss, off);
    int wid = tid >> 6, lane = tid & 63;
    if (lane == 0) swave[wid] = ss;
    __syncthreads();
    float tot = swave[0] + swave[1] + swave[2] + swave[3];
    float scale = 1.f / sqrtf(tot * (1.f / 512.f) + 1e-5f);
    sy[c1] = y1 * scale * norm_w[c1];
    sy[c2] = y2 * scale * norm_w[c2];
    __syncthreads();
    int o = tid & 15, kg = tid >> 4;
    float ps = 0.f;
#pragma unroll
    for (int j = 0; j < 32; j++) {
        int k = kg * 32 + j;
        ps = fmaf(sy[k], Wop[k * 16 + o], ps);
    }
    sred[kg * 16 + o] = ps;
    __syncthreads();
    if (tid < 16) {
        float s = bop[tid];
#pragma unroll
        for (int g = 0; g < 16; g++) s += sred[g * 16 + tid];
        feat[(size_t)node * 16 + tid] = s;
    }
}

// edge MLP + atomic segment-sum: 2 edges per 256-block
__global__ __launch_bounds__(256) void k_msg(const int* __restrict__ src, const int* __restrict__ dst,
        const float* __restrict__ feat, const float* __restrict__ Wm, const float* __restrict__ bm,
        float* __restrict__ agg) {
    int e = blockIdx.x * 2 + (threadIdx.x >> 7);
    int c = threadIdx.x & 127;
    if (e >= N_EDGES_C) return;
    int s = src[e], d = dst[e];
    const float* fr = feat + (size_t)s * 16;
    float m = bm[c];
#pragma unroll
    for (int k = 0; k < 16; k++) m = fmaf(fr[k], Wm[k * 128 + c], m);
    m = fmaxf(m, 0.f);
    atomicAdd(agg + (size_t)d * 128 + c, m);
}

// node update MLP + output head
__global__ __launch_bounds__(128) void k_upd(const float* __restrict__ feat, const float* __restrict__ agg,
        const float* __restrict__ Wu, const float* __restrict__ bu,
        const float* __restrict__ Wo2, const float* __restrict__ bo2,
        float* __restrict__ out) {
    int node = blockIdx.x;
    int c = threadIdx.x;
    __shared__ float sin_[144];
    __shared__ float sw[4];
    if (c < 16) sin_[c] = feat[(size_t)node * 16 + c];
    sin_[16 + c] = agg[(size_t)node * 128 + c];
    __syncthreads();
    float h = bu[c];
#pragma unroll 8
    for (int k = 0; k < 144; k++) h = fmaf(sin_[k], Wu[k * 128 + c], h);
    h = fmaxf(h, 0.f);
    float p0 = h * Wo2[c * 2], p1 = h * Wo2[c * 2 + 1];
#pragma unroll
    for (int off = 32; off >= 1; off >>= 1) {
        p0 += __shfl_xor(p0, off);
        p1 += __shfl_xor(p1, off);
    }
    int lane = c & 63, wid = c >> 6;
    if (lane == 0) { sw[wid] = p0; sw[2 + wid] = p1; }
    __syncthreads();
    if (c == 0) {
        out[(size_t)node * 2 + 0] = sw[0] + sw[1] + bo2[0];
        out[(size_t)node * 2 + 1] = sw[2] + sw[3] + bo2[1];
    }
}

extern "C" void kernel_launch(void* const* d_in, const int* in_sizes, int n_in,
                              void* d_out, int out_size, void* d_ws, size_t ws_size,
                              hipStream_t stream) {
    const float* node_inputs = (const float*)d_in[0];
    const int*   src_ids     = (const int*)d_in[1];
    const int*   dst_ids     = (const int*)d_in[2];
    const float* W_embed     = (const float*)d_in[3];
    const float* b_embed     = (const float*)d_in[4];
    const float* W_in        = (const float*)d_in[5];
    const float* b_in        = (const float*)d_in[6];
    const float* conv_w      = (const float*)d_in[7];
    const float* conv_b      = (const float*)d_in[8];
    const float* A_log       = (const float*)d_in[9];
    const float* dt_bias     = (const float*)d_in[10];
    const float* D_skip      = (const float*)d_in[11];
    const float* norm_w      = (const float*)d_in[12];
    const float* W_outp      = (const float*)d_in[13];
    const float* b_outp      = (const float*)d_in[14];
    const float* W_proj      = (const float*)d_in[15];
    const float* b_proj      = (const float*)d_in[16];
    const float* W_msg       = (const float*)d_in[17];
    const float* b_msg       = (const float*)d_in[18];
    const float* W_upd       = (const float*)d_in[19];
    const float* b_upd       = (const float*)d_in[20];
    const float* W_out       = (const float*)d_in[21];
    const float* b_out       = (const float*)d_in[22];

    float* ws   = (float*)d_ws;
    float* chk  = ws + OFF_CHK;
    float* Wf   = ws + OFF_WF;
    float* bf   = ws + OFF_BF;
    float* Wop  = ws + OFF_WOP;
    float* bop  = ws + OFF_BOP;
    float* xBCc = ws + OFF_XBC;
    float* dtv  = ws + OFF_DTV;
    float* dAv  = ws + OFF_DAV;
    float* ysb  = ws + OFF_YS;
    float* feat = ws + OFF_FEAT;
    float* agg  = ws + OFF_AGG;
    float* out  = (float*)d_out;

    hipMemsetAsync(feat, 0, (size_t)N_NODES_C * 16 * 4, stream);
    hipMemsetAsync(agg, 0, (size_t)N_NODES_C * 128 * 4, stream);

    k_gather<<<(NROWS * 16 + 255) / 256, 256, 0, stream>>>(node_inputs, chk);
    k_fusew<<<(16 * DIP + DIP + DIN * 16 + 16 + 255) / 256, 256, 0, stream>>>(
        W_embed, b_embed, W_in, b_in, W_outp, b_outp, W_proj, b_proj, Wf, bf, Wop, bop);
    k_conv<<<dim3(2, 8, BATCH_C), 320, 0, stream>>>(chk, Wf, bf, conv_w, conv_b, xBCc);
    k_dt<<<(NROWS * NH + 255) / 256, 256, 0, stream>>>(chk, Wf, bf, A_log, dt_bias, dtv, dAv);
    k_scan<<<dim3(NH, BATCH_C), 256, 0, stream>>>(xBCc, dtv, dAv, D_skip, ysb);
    k_gate<<<NROWS, 256, 0, stream>>>(chk, Wf, bf, ysb, norm_w, Wop, bop, feat);
    k_msg<<<N_EDGES_C / 2, 256, 0, stream>>>(src_ids, dst_ids, feat, W_msg, b_msg, agg);
    k_upd<<<N_NODES_C, 128, 0, stream>>>(feat, agg, W_upd, b_upd, W_out, b_out, out);
}

// Round 2
// 925.605 us; speedup vs baseline: 1.3669x; 1.3669x over previous
//
#include <hip/hip_runtime.h>
#include <math.h>

#define LSEQ 624
#define NPG_C 1249
#define BATCH_C 64
#define NROWS (BATCH_C*LSEQ)          // 39936
#define N_NODES_C 79936
#define N_EDGES_C 639488
#define DIP 1160
#define DIN 512
#define CDIM 640
#define NH 8
#define HD 64
#define DS 64

// workspace layout (float offsets)
#define OFF_CHK   0            // 39936*16 = 638976
#define OFF_WF    638976       // 16*1160 = 18560
#define OFF_BF    657536       // 1160
#define OFF_WOP   658944       // 512*16 = 8192
#define OFF_BOP   667136       // 16
#define OFF_XBC   667392       // 39936*640 = 25559040
#define OFF_DTV   26226432     // 39936*8
#define OFF_DAV   26545920     // 39936*8
#define OFF_YS    26865408     // 39936*512 = 20447232
#define OFF_FEAT  47312640     // 79936*16 = 1278976
#define OFF_AGG   48591616     // 79936*128 = 10231808
// total 58823424 floats = 235.3 MB

__device__ __forceinline__ float siluf(float x) {
    return x / (1.f + __expf(-x));
}

// gather check-node rows: chk[row][k] = node_inputs[(row/624)*1249 + row%624][k]
__global__ void k_gather(const float* __restrict__ ni, float* __restrict__ chk) {
    int gid = blockIdx.x * 256 + threadIdx.x;
    if (gid >= NROWS * 16) return;
    int row = gid >> 4, k = gid & 15;
    int node = (row / LSEQ) * NPG_C + (row % LSEQ);
    chk[gid] = ni[node * 16 + k];
}

// fused weights: Wf = W_embed@W_in (16x1160), bf = b_embed@W_in + b_in
//                Wop = W_outp@W_proj (512x16), bop = b_outp@W_proj + b_proj
__global__ void k_fusew(const float* __restrict__ We, const float* __restrict__ be,
                        const float* __restrict__ Wi, const float* __restrict__ bi,
                        const float* __restrict__ Wo, const float* __restrict__ bo,
                        const float* __restrict__ Wp, const float* __restrict__ bp,
                        float* __restrict__ Wf, float* __restrict__ bf,
                        float* __restrict__ Wop, float* __restrict__ bop) {
    int id = blockIdx.x * 256 + threadIdx.x;
    if (id < 16 * DIP) {
        int i = id / DIP, j = id % DIP;
        float s = 0.f;
        for (int k = 0; k < 256; k++) s = fmaf(We[i * 256 + k], Wi[k * DIP + j], s);
        Wf[id] = s;
    } else if (id < 16 * DIP + DIP) {
        int j = id - 16 * DIP;
        float s = bi[j];
        for (int k = 0; k < 256; k++) s = fmaf(be[k], Wi[k * DIP + j], s);
        bf[j] = s;
    } else if (id < 16 * DIP + DIP + DIN * 16) {
        int id2 = id - (16 * DIP + DIP);
        int c = id2 >> 4, o = id2 & 15;
        float s = 0.f;
        for (int k = 0; k < 256; k++) s = fmaf(Wo[c * 256 + k], Wp[k * 16 + o], s);
        Wop[id2] = s;
    } else if (id < 16 * DIP + DIP + DIN * 16 + 16) {
        int o = id - (16 * DIP + DIP + DIN * 16);
        float s = bp[o];
        for (int k = 0; k < 256; k++) s = fmaf(bo[k], Wp[k * 16 + o], s);
        bop[o] = s;
    }
}

// fused in_proj(xBC cols) + causal depthwise conv + silu
// grid (2, 8, 64) block 320: c = bx*320+tid, t-chunk 78, b = bz
__global__ __launch_bounds__(320) void k_conv(const float* __restrict__ chk,
        const float* __restrict__ Wf, const float* __restrict__ bf,
        const float* __restrict__ cw, const float* __restrict__ cb,
        float* __restrict__ xBCc) {
    int c = blockIdx.x * 320 + threadIdx.x;     // 0..639
    int t0 = blockIdx.y * 78;
    int b = blockIdx.z;
    float w[16];
#pragma unroll
    for (int k = 0; k < 16; k++) w[k] = Wf[k * DIP + DIN + c];
    float bfx = bf[DIN + c];
    float k0 = cw[c * 4 + 0], k1 = cw[c * 4 + 1], k2 = cw[c * 4 + 2], k3 = cw[c * 4 + 3];
    float cbv = cb[c];
    const float* crow = chk + (size_t)(b * LSEQ) * 16;
    float* out = xBCc + (size_t)(b * LSEQ) * CDIM + c;

    float w0 = 0.f, w1 = 0.f, w2 = 0.f;
#pragma unroll
    for (int d = 3; d >= 1; d--) {
        int tau = t0 - d;
        float s = 0.f;
        if (tau >= 0) {
            s = bfx;
            const float* cr = crow + tau * 16;
#pragma unroll
            for (int k = 0; k < 16; k++) s = fmaf(cr[k], w[k], s);
        }
        if (d == 3) w0 = s; else if (d == 2) w1 = s; else w2 = s;
    }
    for (int t = t0; t < t0 + 78; t++) {
        const float* cr = crow + t * 16;
        float w3 = bfx;
#pragma unroll
        for (int k = 0; k < 16; k++) w3 = fmaf(cr[k], w[k], w3);
        float a = fmaf(k0, w0, fmaf(k1, w1, fmaf(k2, w2, fmaf(k3, w3, cbv))));
        out[(size_t)t * CDIM] = siluf(a);
        w0 = w1; w1 = w2; w2 = w3;
    }
}

// dt head columns: dt = softplus(chk@Wf_dt + bf_dt + dt_bias); dA = exp(-exp(A_log)*dt)
__global__ void k_dt(const float* __restrict__ chk, const float* __restrict__ Wf,
                     const float* __restrict__ bf, const float* __restrict__ A_log,
                     const float* __restrict__ dt_bias,
                     float* __restrict__ dtv, float* __restrict__ dAv) {
    int id = blockIdx.x * 256 + threadIdx.x;
    if (id >= NROWS * NH) return;
    int row = id >> 3, h = id & 7;
    const float* cr = chk + (size_t)row * 16;
    float s = bf[DIN + CDIM + h];
#pragma unroll
    for (int k = 0; k < 16; k++) s = fmaf(cr[k], Wf[k * DIP + DIN + CDIM + h], s);
    s += dt_bias[h];
    float sp = (s > 20.f) ? s : log1pf(__expf(s));
    dtv[id] = sp;
    dAv[id] = __expf(-__expf(A_log[h]) * sp);
}

// selective scan, LDS double-buffered staging version.
// One block per (head, b); 256 thr; thread owns p=tid>>2, states [q*16,q*16+16), q=tid&3.
// Chunks of TC=48 timesteps staged in LDS: per t: [x(64) | B(64) | C(64)] = 192 floats.
#define TC 48
#define NCH 13
#define SEGF 192
#define CHF (TC*SEGF)   // 9216 floats per buffer
__global__ __launch_bounds__(256) void k_scan(const float* __restrict__ xBCc,
        const float* __restrict__ dtv, const float* __restrict__ dAv,
        const float* __restrict__ Dskip, float* __restrict__ ys) {
    int head = blockIdx.x;
    int b = blockIdx.y;
    int tid = threadIdx.x;
    int p = tid >> 2, q = tid & 3;
    int q16 = q * 16;

    __shared__ float sbuf[2][CHF];
    __shared__ float sa[2][TC];
    __shared__ float sd[2][TC];

    const int bs = b * LSEQ;
    const float* dAp = dAv + (size_t)bs * NH + head;
    const float* dtp = dtv + (size_t)bs * NH + head;
    float* yp = ys + (size_t)bs * DIN + head * HD + p;
    float dsk = Dskip[head];

    // per-thread staging: 9 float4 (g = j*256+tid in float4 units; CHF/4 = 2304 = 9*256)
    // flat float f = 4g; t = g/48; seg = 4*(g%48); col = seg<64 ? head*64+seg : 448+seg
    float4 rg[9];
    float ra = 0.f, rd = 0.f;

#define ISSUE_LOADS(c1)                                                          \
    {                                                                            \
        int trow0 = bs + (c1) * TC;                                              \
        _Pragma("unroll")                                                        \
        for (int j = 0; j < 9; j++) {                                            \
            int g = j * 256 + tid;                                               \
            int t = g / 48;                                                      \
            int seg = 4 * (g - t * 48);                                          \
            int col = (seg < 64) ? (head * HD + seg) : (448 + seg);              \
            rg[j] = *(const float4*)(xBCc + (size_t)(trow0 + t) * CDIM + col);   \
        }                                                                        \
        if (tid < TC)                   ra = dAp[(size_t)((c1) * TC + tid) * NH];\
        else if (tid >= 64 && tid < 64 + TC) rd = dtp[(size_t)((c1) * TC + tid - 64) * NH]; \
    }

#define WRITE_LDS(nb)                                                            \
    {                                                                            \
        _Pragma("unroll")                                                        \
        for (int j = 0; j < 9; j++) {                                            \
            int g = j * 256 + tid;                                               \
            *(float4*)&sbuf[nb][g * 4] = rg[j];                                  \
        }                                                                        \
        if (tid < TC) sa[nb][tid] = ra;                                          \
        else if (tid >= 64 && tid < 64 + TC) sd[nb][tid - 64] = rd;              \
    }

    float h[16];
#pragma unroll
    for (int i = 0; i < 16; i++) h[i] = 0.f;

    // prologue: stage chunk 0
    ISSUE_LOADS(0);
    WRITE_LDS(0);
    __syncthreads();

    int cur = 0;
    for (int c = 0; c < NCH; c++) {
        if (c + 1 < NCH) ISSUE_LOADS(c + 1);       // in-flight during compute

        const float* bufc = &sbuf[cur][0];
        const float* sac = &sa[cur][0];
        const float* sdc = &sd[cur][0];
#pragma unroll 4
        for (int t = 0; t < TC; t++) {
            int tb = t * SEGF;
            float a = sac[t];
            float d = sdc[t];
            float xv = bufc[tb + p];
            float4 B0 = *(const float4*)&bufc[tb + 64 + q16];
            float4 B1 = *(const float4*)&bufc[tb + 64 + q16 + 4];
            float4 B2 = *(const float4*)&bufc[tb + 64 + q16 + 8];
            float4 B3 = *(const float4*)&bufc[tb + 64 + q16 + 12];
            float4 C0 = *(const float4*)&bufc[tb + 128 + q16];
            float4 C1 = *(const float4*)&bufc[tb + 128 + q16 + 4];
            float4 C2 = *(const float4*)&bufc[tb + 128 + q16 + 8];
            float4 C3 = *(const float4*)&bufc[tb + 128 + q16 + 12];
            float dx = d * xv;
            float acc = 0.f;
            h[0]  = fmaf(a, h[0],  dx * B0.x); acc = fmaf(h[0],  C0.x, acc);
            h[1]  = fmaf(a, h[1],  dx * B0.y); acc = fmaf(h[1],  C0.y, acc);
            h[2]  = fmaf(a, h[2],  dx * B0.z); acc = fmaf(h[2],  C0.z, acc);
            h[3]  = fmaf(a, h[3],  dx * B0.w); acc = fmaf(h[3],  C0.w, acc);
            h[4]  = fmaf(a, h[4],  dx * B1.x); acc = fmaf(h[4],  C1.x, acc);
            h[5]  = fmaf(a, h[5],  dx * B1.y); acc = fmaf(h[5],  C1.y, acc);
            h[6]  = fmaf(a, h[6],  dx * B1.z); acc = fmaf(h[6],  C1.z, acc);
            h[7]  = fmaf(a, h[7],  dx * B1.w); acc = fmaf(h[7],  C1.w, acc);
            h[8]  = fmaf(a, h[8],  dx * B2.x); acc = fmaf(h[8],  C2.x, acc);
            h[9]  = fmaf(a, h[9],  dx * B2.y); acc = fmaf(h[9],  C2.y, acc);
            h[10] = fmaf(a, h[10], dx * B2.z); acc = fmaf(h[10], C2.z, acc);
            h[11] = fmaf(a, h[11], dx * B2.w); acc = fmaf(h[11], C2.w, acc);
            h[12] = fmaf(a, h[12], dx * B3.x); acc = fmaf(h[12], C3.x, acc);
            h[13] = fmaf(a, h[13], dx * B3.y); acc = fmaf(h[13], C3.y, acc);
            h[14] = fmaf(a, h[14], dx * B3.z); acc = fmaf(h[14], C3.z, acc);
            h[15] = fmaf(a, h[15], dx * B3.w); acc = fmaf(h[15], C3.w, acc);
            acc += __shfl_xor(acc, 1);
            acc += __shfl_xor(acc, 2);
            if (q == 0) yp[(size_t)(c * TC + t) * DIN] = fmaf(dsk, xv, acc);
        }

        if (c + 1 < NCH) WRITE_LDS(cur ^ 1);       // waits vmcnt internally
        __syncthreads();
        cur ^= 1;
    }
#undef ISSUE_LOADS
#undef WRITE_LDS
}

// gate (recompute z) + RMSNorm + fused out_proj@proj + scatter into feat
__global__ __launch_bounds__(256) void k_gate(const float* __restrict__ chk,
        const float* __restrict__ Wf, const float* __restrict__ bf,
        const float* __restrict__ ysb, const float* __restrict__ norm_w,
        const float* __restrict__ Wop, const float* __restrict__ bop,
        float* __restrict__ feat) {
    int row = blockIdx.x;
    int tid = threadIdx.x;
    int b = row / LSEQ, t = row % LSEQ;
    int node = b * NPG_C + t;
    __shared__ float sy[512];
    __shared__ float sred[256];
    __shared__ float swave[4];

    float cv[16];
    const float* cr = chk + (size_t)row * 16;
#pragma unroll
    for (int k = 0; k < 16; k++) cv[k] = cr[k];
    int c1 = tid, c2 = tid + 256;
    float z1 = bf[c1], z2 = bf[c2];
#pragma unroll
    for (int k = 0; k < 16; k++) {
        z1 = fmaf(cv[k], Wf[k * DIP + c1], z1);
        z2 = fmaf(cv[k], Wf[k * DIP + c2], z2);
    }
    float y1 = ysb[(size_t)row * DIN + c1] * siluf(z1);
    float y2 = ysb[(size_t)row * DIN + c2] * siluf(z2);
    float ss = y1 * y1 + y2 * y2;
#pragma unroll
    for (int off = 32; off >= 1; off >>= 1) ss += __shfl_xor(ss, off);
    int wid = tid >> 6, lane = tid & 63;
    if (lane == 0) swave[wid] = ss;
    __syncthreads();
    float tot = swave[0] + swave[1] + swave[2] + swave[3];
    float scale = 1.f / sqrtf(tot * (1.f / 512.f) + 1e-5f);
    sy[c1] = y1 * scale * norm_w[c1];
    sy[c2] = y2 * scale * norm_w[c2];
    __syncthreads();
    int o = tid & 15, kg = tid >> 4;
    float ps = 0.f;
#pragma unroll
    for (int j = 0; j < 32; j++) {
        int k = kg * 32 + j;
        ps = fmaf(sy[k], Wop[k * 16 + o], ps);
    }
    sred[kg * 16 + o] = ps;
    __syncthreads();
    if (tid < 16) {
        float s = bop[tid];
#pragma unroll
        for (int g = 0; g < 16; g++) s += sred[g * 16 + tid];
        feat[(size_t)node * 16 + tid] = s;
    }
}

// edge MLP + atomic segment-sum: 2 edges per 256-block
__global__ __launch_bounds__(256) void k_msg(const int* __restrict__ src, const int* __restrict__ dst,
        const float* __restrict__ feat, const float* __restrict__ Wm, const float* __restrict__ bm,
        float* __restrict__ agg) {
    int e = blockIdx.x * 2 + (threadIdx.x >> 7);
    int c = threadIdx.x & 127;
    if (e >= N_EDGES_C) return;
    int s = src[e], d = dst[e];
    const float* fr = feat + (size_t)s * 16;
    float m = bm[c];
#pragma unroll
    for (int k = 0; k < 16; k++) m = fmaf(fr[k], Wm[k * 128 + c], m);
    m = fmaxf(m, 0.f);
    atomicAdd(agg + (size_t)d * 128 + c, m);
}

// node update MLP + output head
__global__ __launch_bounds__(128) void k_upd(const float* __restrict__ feat, const float* __restrict__ agg,
        const float* __restrict__ Wu, const float* __restrict__ bu,
        const float* __restrict__ Wo2, const float* __restrict__ bo2,
        float* __restrict__ out) {
    int node = blockIdx.x;
    int c = threadIdx.x;
    __shared__ float sin_[144];
    __shared__ float sw[4];
    if (c < 16) sin_[c] = feat[(size_t)node * 16 + c];
    sin_[16 + c] = agg[(size_t)node * 128 + c];
    __syncthreads();
    float h = bu[c];
#pragma unroll 8
    for (int k = 0; k < 144; k++) h = fmaf(sin_[k], Wu[k * 128 + c], h);
    h = fmaxf(h, 0.f);
    float p0 = h * Wo2[c * 2], p1 = h * Wo2[c * 2 + 1];
#pragma unroll
    for (int off = 32; off >= 1; off >>= 1) {
        p0 += __shfl_xor(p0, off);
        p1 += __shfl_xor(p1, off);
    }
    int lane = c & 63, wid = c >> 6;
    if (lane == 0) { sw[wid] = p0; sw[2 + wid] = p1; }
    __syncthreads();
    if (c == 0) {
        out[(size_t)node * 2 + 0] = sw[0] + sw[1] + bo2[0];
        out[(size_t)node * 2 + 1] = sw[2] + sw[3] + bo2[1];
    }
}

extern "C" void kernel_launch(void* const* d_in, const int* in_sizes, int n_in,
                              void* d_out, int out_size, void* d_ws, size_t ws_size,
                              hipStream_t stream) {
    const float* node_inputs = (const float*)d_in[0];
    const int*   src_ids     = (const int*)d_in[1];
    const int*   dst_ids     = (const int*)d_in[2];
    const float* W_embed     = (const float*)d_in[3];
    const float* b_embed     = (const float*)d_in[4];
    const float* W_in        = (const float*)d_in[5];
    const float* b_in        = (const float*)d_in[6];
    const float* conv_w      = (const float*)d_in[7];
    const float* conv_b      = (const float*)d_in[8];
    const float* A_log       = (const float*)d_in[9];
    const float* dt_bias     = (const float*)d_in[10];
    const float* D_skip      = (const float*)d_in[11];
    const float* norm_w      = (const float*)d_in[12];
    const float* W_outp      = (const float*)d_in[13];
    const float* b_outp      = (const float*)d_in[14];
    const float* W_proj      = (const float*)d_in[15];
    const float* b_proj      = (const float*)d_in[16];
    const float* W_msg       = (const float*)d_in[17];
    const float* b_msg       = (const float*)d_in[18];
    const float* W_upd       = (const float*)d_in[19];
    const float* b_upd       = (const float*)d_in[20];
    const float* W_out       = (const float*)d_in[21];
    const float* b_out       = (const float*)d_in[22];

    float* ws   = (float*)d_ws;
    float* chk  = ws + OFF_CHK;
    float* Wf   = ws + OFF_WF;
    float* bf   = ws + OFF_BF;
    float* Wop  = ws + OFF_WOP;
    float* bop  = ws + OFF_BOP;
    float* xBCc = ws + OFF_XBC;
    float* dtv  = ws + OFF_DTV;
    float* dAv  = ws + OFF_DAV;
    float* ysb  = ws + OFF_YS;
    float* feat = ws + OFF_FEAT;
    float* agg  = ws + OFF_AGG;
    float* out  = (float*)d_out;

    hipMemsetAsync(feat, 0, (size_t)N_NODES_C * 16 * 4, stream);
    hipMemsetAsync(agg, 0, (size_t)N_NODES_C * 128 * 4, stream);

    k_gather<<<(NROWS * 16 + 255) / 256, 256, 0, stream>>>(node_inputs, chk);
    k_fusew<<<(16 * DIP + DIP + DIN * 16 + 16 + 255) / 256, 256, 0, stream>>>(
        W_embed, b_embed, W_in, b_in, W_outp, b_outp, W_proj, b_proj, Wf, bf, Wop, bop);
    k_conv<<<dim3(2, 8, BATCH_C), 320, 0, stream>>>(chk, Wf, bf, conv_w, conv_b, xBCc);
    k_dt<<<(NROWS * NH + 255) / 256, 256, 0, stream>>>(chk, Wf, bf, A_log, dt_bias, dtv, dAv);
    k_scan<<<dim3(NH, BATCH_C), 256, 0, stream>>>(xBCc, dtv, dAv, D_skip, ysb);
    k_gate<<<NROWS, 256, 0, stream>>>(chk, Wf, bf, ysb, norm_w, Wop, bop, feat);
    k_msg<<<N_EDGES_C / 2, 256, 0, stream>>>(src_ids, dst_ids, feat, W_msg, b_msg, agg);
    k_upd<<<N_NODES_C, 128, 0, stream>>>(feat, agg, W_upd, b_upd, W_out, b_out, out);
}

// Round 3
// 695.734 us; speedup vs baseline: 1.8185x; 1.3304x over previous
//
#include <hip/hip_runtime.h>
#include <math.h>

#define LSEQ 624
#define NPG_C 1249
#define BATCH_C 64
#define NROWS (BATCH_C*LSEQ)          // 39936
#define N_NODES_C 79936
#define N_EDGES_C 639488
#define DIP 1160
#define DIN 512
#define CDIM 640
#define NH 8
#define HD 64
#define DS 64
#define CAP 96

// workspace layout (float offsets)
#define OFF_CHK   0            // 39936*16 = 638976
#define OFF_WF    638976       // 16*1160 = 18560
#define OFF_BF    657536       // 1160
#define OFF_WOP   658944       // 512*16 = 8192
#define OFF_BOP   667136       // 16
#define OFF_XBC   667392       // 39936*640 = 25559040  (reused as slots after scan)
#define OFF_DTV   26226432     // 39936*8              (reused as cnt after scan)
#define OFF_DAV   26545920     // 39936*8
#define OFF_YS    26865408     // 39936*512 = 20447232
#define OFF_FEAT  47312640     // 79936*16 = 1278976
#define OFF_AGG   48591616     // 79936*128 = 10231808
// total 58823424 floats = 235.3 MB

__device__ __forceinline__ float siluf(float x) {
    return x / (1.f + __expf(-x));
}

// gather check-node rows
__global__ void k_gather(const float* __restrict__ ni, float* __restrict__ chk) {
    int gid = blockIdx.x * 256 + threadIdx.x;
    if (gid >= NROWS * 16) return;
    int row = gid >> 4, k = gid & 15;
    int node = (row / LSEQ) * NPG_C + (row % LSEQ);
    chk[gid] = ni[node * 16 + k];
}

// fused weights
__global__ void k_fusew(const float* __restrict__ We, const float* __restrict__ be,
                        const float* __restrict__ Wi, const float* __restrict__ bi,
                        const float* __restrict__ Wo, const float* __restrict__ bo,
                        const float* __restrict__ Wp, const float* __restrict__ bp,
                        float* __restrict__ Wf, float* __restrict__ bf,
                        float* __restrict__ Wop, float* __restrict__ bop) {
    int id = blockIdx.x * 256 + threadIdx.x;
    if (id < 16 * DIP) {
        int i = id / DIP, j = id % DIP;
        float s = 0.f;
        for (int k = 0; k < 256; k++) s = fmaf(We[i * 256 + k], Wi[k * DIP + j], s);
        Wf[id] = s;
    } else if (id < 16 * DIP + DIP) {
        int j = id - 16 * DIP;
        float s = bi[j];
        for (int k = 0; k < 256; k++) s = fmaf(be[k], Wi[k * DIP + j], s);
        bf[j] = s;
    } else if (id < 16 * DIP + DIP + DIN * 16) {
        int id2 = id - (16 * DIP + DIP);
        int c = id2 >> 4, o = id2 & 15;
        float s = 0.f;
        for (int k = 0; k < 256; k++) s = fmaf(Wo[c * 256 + k], Wp[k * 16 + o], s);
        Wop[id2] = s;
    } else if (id < 16 * DIP + DIP + DIN * 16 + 16) {
        int o = id - (16 * DIP + DIP + DIN * 16);
        float s = bp[o];
        for (int k = 0; k < 256; k++) s = fmaf(bo[k], Wp[k * 16 + o], s);
        bop[o] = s;
    }
}

// fused in_proj(xBC cols) + causal depthwise conv + silu
__global__ __launch_bounds__(320) void k_conv(const float* __restrict__ chk,
        const float* __restrict__ Wf, const float* __restrict__ bf,
        const float* __restrict__ cw, const float* __restrict__ cb,
        float* __restrict__ xBCc) {
    int c = blockIdx.x * 320 + threadIdx.x;     // 0..639
    int t0 = blockIdx.y * 78;
    int b = blockIdx.z;
    float w[16];
#pragma unroll
    for (int k = 0; k < 16; k++) w[k] = Wf[k * DIP + DIN + c];
    float bfx = bf[DIN + c];
    float k0 = cw[c * 4 + 0], k1 = cw[c * 4 + 1], k2 = cw[c * 4 + 2], k3 = cw[c * 4 + 3];
    float cbv = cb[c];
    const float* crow = chk + (size_t)(b * LSEQ) * 16;
    float* out = xBCc + (size_t)(b * LSEQ) * CDIM + c;

    float w0 = 0.f, w1 = 0.f, w2 = 0.f;
#pragma unroll
    for (int d = 3; d >= 1; d--) {
        int tau = t0 - d;
        float s = 0.f;
        if (tau >= 0) {
            s = bfx;
            const float* cr = crow + tau * 16;
#pragma unroll
            for (int k = 0; k < 16; k++) s = fmaf(cr[k], w[k], s);
        }
        if (d == 3) w0 = s; else if (d == 2) w1 = s; else w2 = s;
    }
    for (int t = t0; t < t0 + 78; t++) {
        const float* cr = crow + t * 16;
        float w3 = bfx;
#pragma unroll
        for (int k = 0; k < 16; k++) w3 = fmaf(cr[k], w[k], w3);
        float a = fmaf(k0, w0, fmaf(k1, w1, fmaf(k2, w2, fmaf(k3, w3, cbv))));
        out[(size_t)t * CDIM] = siluf(a);
        w0 = w1; w1 = w2; w2 = w3;
    }
}

// dt head columns
__global__ void k_dt(const float* __restrict__ chk, const float* __restrict__ Wf,
                     const float* __restrict__ bf, const float* __restrict__ A_log,
                     const float* __restrict__ dt_bias,
                     float* __restrict__ dtv, float* __restrict__ dAv) {
    int id = blockIdx.x * 256 + threadIdx.x;
    if (id >= NROWS * NH) return;
    int row = id >> 3, h = id & 7;
    const float* cr = chk + (size_t)row * 16;
    float s = bf[DIN + CDIM + h];
#pragma unroll
    for (int k = 0; k < 16; k++) s = fmaf(cr[k], Wf[k * DIP + DIN + CDIM + h], s);
    s += dt_bias[h];
    float sp = (s > 20.f) ? s : log1pf(__expf(s));
    dtv[id] = sp;
    dAv[id] = __expf(-__expf(A_log[h]) * sp);
}

// selective scan, LDS double-buffered, 4p x 4n per-thread tile.
// One block per (head, b); 256 thr; i = tid>>4 owns p in [4i,4i+4); j = tid&15 owns n in [4j,4j+4).
#define TC 48
#define NCH 13
#define SEGF 192
#define CHF (TC*SEGF)   // 9216 floats per buffer
__global__ __launch_bounds__(256) void k_scan(const float* __restrict__ xBCc,
        const float* __restrict__ dtv, const float* __restrict__ dAv,
        const float* __restrict__ Dskip, float* __restrict__ ys) {
    int head = blockIdx.x;
    int b = blockIdx.y;
    int tid = threadIdx.x;
    int i4 = (tid >> 4) * 4;    // p base
    int j4 = (tid & 15) * 4;    // n base

    __shared__ float sbuf[2][CHF];
    __shared__ float sa[2][TC];
    __shared__ float sd[2][TC];

    const int bs = b * LSEQ;
    const float* dAp = dAv + (size_t)bs * NH + head;
    const float* dtp = dtv + (size_t)bs * NH + head;
    float* yq = ys + (size_t)bs * DIN + head * HD + i4;
    float dsk = Dskip[head];

    float4 rg[9];
    float ra = 0.f, rd = 0.f;

#define ISSUE_LOADS(c1)                                                          \
    {                                                                            \
        int trow0 = bs + (c1) * TC;                                              \
        _Pragma("unroll")                                                        \
        for (int jj = 0; jj < 9; jj++) {                                         \
            int g = jj * 256 + tid;                                              \
            int t = g / 48;                                                      \
            int seg = 4 * (g - t * 48);                                          \
            int col = (seg < 64) ? (head * HD + seg) : (448 + seg);              \
            rg[jj] = *(const float4*)(xBCc + (size_t)(trow0 + t) * CDIM + col);  \
        }                                                                        \
        if (tid < TC)                   ra = dAp[(size_t)((c1) * TC + tid) * NH];\
        else if (tid >= 64 && tid < 64 + TC) rd = dtp[(size_t)((c1) * TC + tid - 64) * NH]; \
    }

#define WRITE_LDS(nb)                                                            \
    {                                                                            \
        _Pragma("unroll")                                                        \
        for (int jj = 0; jj < 9; jj++) {                                         \
            int g = jj * 256 + tid;                                              \
            *(float4*)&sbuf[nb][g * 4] = rg[jj];                                 \
        }                                                                        \
        if (tid < TC) sa[nb][tid] = ra;                                          \
        else if (tid >= 64 && tid < 64 + TC) sd[nb][tid - 64] = rd;              \
    }

    float h[16];
#pragma unroll
    for (int e = 0; e < 16; e++) h[e] = 0.f;

    ISSUE_LOADS(0);
    WRITE_LDS(0);
    __syncthreads();

    int cur = 0;
    for (int ch = 0; ch < NCH; ch++) {
        if (ch + 1 < NCH) ISSUE_LOADS(ch + 1);

        const float* bufc = &sbuf[cur][0];
        const float* sac = &sa[cur][0];
        const float* sdc = &sd[cur][0];
#pragma unroll 4
        for (int t = 0; t < TC; t++) {
            int tb = t * SEGF;
            float a = sac[t];
            float d = sdc[t];
            float4 xv = *(const float4*)&bufc[tb + i4];
            float4 Bv = *(const float4*)&bufc[tb + 64 + j4];
            float4 Cv = *(const float4*)&bufc[tb + 128 + j4];
            float dx0 = d * xv.x, dx1 = d * xv.y, dx2 = d * xv.z, dx3 = d * xv.w;
            float acc0 = 0.f, acc1 = 0.f, acc2 = 0.f, acc3 = 0.f;
            h[0]  = fmaf(a, h[0],  dx0 * Bv.x); acc0 = fmaf(h[0],  Cv.x, acc0);
            h[1]  = fmaf(a, h[1],  dx0 * Bv.y); acc0 = fmaf(h[1],  Cv.y, acc0);
            h[2]  = fmaf(a, h[2],  dx0 * Bv.z); acc0 = fmaf(h[2],  Cv.z, acc0);
            h[3]  = fmaf(a, h[3],  dx0 * Bv.w); acc0 = fmaf(h[3],  Cv.w, acc0);
            h[4]  = fmaf(a, h[4],  dx1 * Bv.x); acc1 = fmaf(h[4],  Cv.x, acc1);
            h[5]  = fmaf(a, h[5],  dx1 * Bv.y); acc1 = fmaf(h[5],  Cv.y, acc1);
            h[6]  = fmaf(a, h[6],  dx1 * Bv.z); acc1 = fmaf(h[6],  Cv.z, acc1);
            h[7]  = fmaf(a, h[7],  dx1 * Bv.w); acc1 = fmaf(h[7],  Cv.w, acc1);
            h[8]  = fmaf(a, h[8],  dx2 * Bv.x); acc2 = fmaf(h[8],  Cv.x, acc2);
            h[9]  = fmaf(a, h[9],  dx2 * Bv.y); acc2 = fmaf(h[9],  Cv.y, acc2);
            h[10] = fmaf(a, h[10], dx2 * Bv.z); acc2 = fmaf(h[10], Cv.z, acc2);
            h[11] = fmaf(a, h[11], dx2 * Bv.w); acc2 = fmaf(h[11], Cv.w, acc2);
            h[12] = fmaf(a, h[12], dx3 * Bv.x); acc3 = fmaf(h[12], Cv.x, acc3);
            h[13] = fmaf(a, h[13], dx3 * Bv.y); acc3 = fmaf(h[13], Cv.y, acc3);
            h[14] = fmaf(a, h[14], dx3 * Bv.z); acc3 = fmaf(h[14], Cv.z, acc3);
            h[15] = fmaf(a, h[15], dx3 * Bv.w); acc3 = fmaf(h[15], Cv.w, acc3);
#pragma unroll
            for (int off = 1; off < 16; off <<= 1) {
                acc0 += __shfl_xor(acc0, off);
                acc1 += __shfl_xor(acc1, off);
                acc2 += __shfl_xor(acc2, off);
                acc3 += __shfl_xor(acc3, off);
            }
            if (j4 == 0) {
                float4 o4;
                o4.x = fmaf(dsk, xv.x, acc0);
                o4.y = fmaf(dsk, xv.y, acc1);
                o4.z = fmaf(dsk, xv.z, acc2);
                o4.w = fmaf(dsk, xv.w, acc3);
                *(float4*)&yq[(size_t)(ch * TC + t) * DIN] = o4;
            }
        }

        if (ch + 1 < NCH) WRITE_LDS(cur ^ 1);
        __syncthreads();
        cur ^= 1;
    }
#undef ISSUE_LOADS
#undef WRITE_LDS
}

// gate (recompute z) + RMSNorm + fused out_proj@proj + scatter into feat
__global__ __launch_bounds__(256) void k_gate(const float* __restrict__ chk,
        const float* __restrict__ Wf, const float* __restrict__ bf,
        const float* __restrict__ ysb, const float* __restrict__ norm_w,
        const float* __restrict__ Wop, const float* __restrict__ bop,
        float* __restrict__ feat) {
    int row = blockIdx.x;
    int tid = threadIdx.x;
    int b = row / LSEQ, t = row % LSEQ;
    int node = b * NPG_C + t;
    __shared__ float sy[512];
    __shared__ float sred[256];
    __shared__ float swave[4];

    float cv[16];
    const float* cr = chk + (size_t)row * 16;
#pragma unroll
    for (int k = 0; k < 16; k++) cv[k] = cr[k];
    int c1 = tid, c2 = tid + 256;
    float z1 = bf[c1], z2 = bf[c2];
#pragma unroll
    for (int k = 0; k < 16; k++) {
        z1 = fmaf(cv[k], Wf[k * DIP + c1], z1);
        z2 = fmaf(cv[k], Wf[k * DIP + c2], z2);
    }
    float y1 = ysb[(size_t)row * DIN + c1] * siluf(z1);
    float y2 = ysb[(size_t)row * DIN + c2] * siluf(z2);
    float ss = y1 * y1 + y2 * y2;
#pragma unroll
    for (int off = 32; off >= 1; off >>= 1) ss += __shfl_xor(ss, off);
    int wid = tid >> 6, lane = tid & 63;
    if (lane == 0) swave[wid] = ss;
    __syncthreads();
    float tot = swave[0] + swave[1] + swave[2] + swave[3];
    float scale = 1.f / sqrtf(tot * (1.f / 512.f) + 1e-5f);
    sy[c1] = y1 * scale * norm_w[c1];
    sy[c2] = y2 * scale * norm_w[c2];
    __syncthreads();
    int o = tid & 15, kg = tid >> 4;
    float ps = 0.f;
#pragma unroll
    for (int j = 0; j < 32; j++) {
        int k = kg * 32 + j;
        ps = fmaf(sy[k], Wop[k * 16 + o], ps);
    }
    sred[kg * 16 + o] = ps;
    __syncthreads();
    if (tid < 16) {
        float s = bop[tid];
#pragma unroll
        for (int g = 0; g < 16; g++) s += sred[g * 16 + tid];
        feat[(size_t)node * 16 + tid] = s;
    }
}

// build per-dst adjacency: cnt (int) + slot list of src ids
__global__ void k_scatter(const int* __restrict__ src, const int* __restrict__ dst,
                          int* __restrict__ cnt, int* __restrict__ slots) {
    int e = blockIdx.x * 256 + threadIdx.x;
    if (e >= N_EDGES_C) return;
    int d = dst[e];
    int pos = atomicAdd(&cnt[d], 1);
    if (pos < CAP) slots[(size_t)d * CAP + pos] = src[e];
}

// dst-centric aggregate: block per node, thread per channel
__global__ __launch_bounds__(128) void k_agg(const int* __restrict__ cnt,
        const int* __restrict__ slots, const float* __restrict__ feat,
        const float* __restrict__ Wm, const float* __restrict__ bm,
        float* __restrict__ agg) {
    int d = blockIdx.x, c = threadIdx.x;
    int deg = cnt[d];
    if (deg > CAP) deg = CAP;
    float w[16];
#pragma unroll
    for (int k = 0; k < 16; k++) w[k] = Wm[k * 128 + c];
    float bmv = bm[c];
    float acc = 0.f;
    const int* sl = slots + (size_t)d * CAP;
    for (int e = 0; e < deg; e++) {
        int s = __builtin_amdgcn_readfirstlane(sl[e]);
        const float4* fr = (const float4*)(feat + (size_t)s * 16);
        float4 f0 = fr[0], f1 = fr[1], f2 = fr[2], f3 = fr[3];
        float m = bmv;
        m = fmaf(f0.x, w[0],  m); m = fmaf(f0.y, w[1],  m);
        m = fmaf(f0.z, w[2],  m); m = fmaf(f0.w, w[3],  m);
        m = fmaf(f1.x, w[4],  m); m = fmaf(f1.y, w[5],  m);
        m = fmaf(f1.z, w[6],  m); m = fmaf(f1.w, w[7],  m);
        m = fmaf(f2.x, w[8],  m); m = fmaf(f2.y, w[9],  m);
        m = fmaf(f2.z, w[10], m); m = fmaf(f2.w, w[11], m);
        m = fmaf(f3.x, w[12], m); m = fmaf(f3.y, w[13], m);
        m = fmaf(f3.z, w[14], m); m = fmaf(f3.w, w[15], m);
        acc += fmaxf(m, 0.f);
    }
    agg[(size_t)d * 128 + c] = acc;
}

// node update MLP + output head, 16 nodes per block
#define UNB 16
__global__ __launch_bounds__(256) void k_upd2(const float* __restrict__ feat,
        const float* __restrict__ agg, const float* __restrict__ Wu,
        const float* __restrict__ bu, const float* __restrict__ Wo2,
        const float* __restrict__ bo2, float* __restrict__ out) {
    int g0 = blockIdx.x * UNB;
    int tid = threadIdx.x;
    __shared__ __align__(16) float sin_[UNB][144];
    __shared__ float part[4][8][2];
    for (int w = tid; w < UNB * 144; w += 256) {
        int node = w / 144, k = w - node * 144;
        sin_[node][k] = (k < 16) ? feat[(size_t)(g0 + node) * 16 + k]
                                 : agg[(size_t)(g0 + node) * 128 + (k - 16)];
    }
    __syncthreads();
    int rr = tid >> 7, c = tid & 127;
    float acc[8];
#pragma unroll
    for (int nn = 0; nn < 8; nn++) acc[nn] = 0.f;
    for (int k0 = 0; k0 < 144; k0 += 4) {
        float wu0 = Wu[(k0 + 0) * 128 + c];
        float wu1 = Wu[(k0 + 1) * 128 + c];
        float wu2 = Wu[(k0 + 2) * 128 + c];
        float wu3 = Wu[(k0 + 3) * 128 + c];
#pragma unroll
        for (int nn = 0; nn < 8; nn++) {
            float4 s4 = *(const float4*)&sin_[rr * 8 + nn][k0];
            acc[nn] = fmaf(s4.x, wu0, acc[nn]);
            acc[nn] = fmaf(s4.y, wu1, acc[nn]);
            acc[nn] = fmaf(s4.z, wu2, acc[nn]);
            acc[nn] = fmaf(s4.w, wu3, acc[nn]);
        }
    }
    float buc = bu[c];
    float w0 = Wo2[c * 2], w1 = Wo2[c * 2 + 1];
    float p[8][2];
#pragma unroll
    for (int nn = 0; nn < 8; nn++) {
        float h = fmaxf(acc[nn] + buc, 0.f);
        p[nn][0] = h * w0;
        p[nn][1] = h * w1;
    }
#pragma unroll
    for (int off = 1; off < 64; off <<= 1) {
#pragma unroll
        for (int nn = 0; nn < 8; nn++) {
            p[nn][0] += __shfl_xor(p[nn][0], off);
            p[nn][1] += __shfl_xor(p[nn][1], off);
        }
    }
    int wv = tid >> 6;
    if ((tid & 63) == 0) {
#pragma unroll
        for (int nn = 0; nn < 8; nn++) {
            part[wv][nn][0] = p[nn][0];
            part[wv][nn][1] = p[nn][1];
        }
    }
    __syncthreads();
    if (tid < 32) {
        int o = tid & 1, nn = (tid >> 1) & 7, r2 = tid >> 4;
        float v = part[r2 * 2 + 0][nn][o] + part[r2 * 2 + 1][nn][o] + bo2[o];
        out[(size_t)(g0 + r2 * 8 + nn) * 2 + o] = v;
    }
}

extern "C" void kernel_launch(void* const* d_in, const int* in_sizes, int n_in,
                              void* d_out, int out_size, void* d_ws, size_t ws_size,
                              hipStream_t stream) {
    const float* node_inputs = (const float*)d_in[0];
    const int*   src_ids     = (const int*)d_in[1];
    const int*   dst_ids     = (const int*)d_in[2];
    const float* W_embed     = (const float*)d_in[3];
    const float* b_embed     = (const float*)d_in[4];
    const float* W_in        = (const float*)d_in[5];
    const float* b_in        = (const float*)d_in[6];
    const float* conv_w      = (const float*)d_in[7];
    const float* conv_b      = (const float*)d_in[8];
    const float* A_log       = (const float*)d_in[9];
    const float* dt_bias     = (const float*)d_in[10];
    const float* D_skip      = (const float*)d_in[11];
    const float* norm_w      = (const float*)d_in[12];
    const float* W_outp      = (const float*)d_in[13];
    const float* b_outp      = (const float*)d_in[14];
    const float* W_proj      = (const float*)d_in[15];
    const float* b_proj      = (const float*)d_in[16];
    const float* W_msg       = (const float*)d_in[17];
    const float* b_msg       = (const float*)d_in[18];
    const float* W_upd       = (const float*)d_in[19];
    const float* b_upd       = (const float*)d_in[20];
    const float* W_out       = (const float*)d_in[21];
    const float* b_out       = (const float*)d_in[22];

    float* ws   = (float*)d_ws;
    float* chk  = ws + OFF_CHK;
    float* Wf   = ws + OFF_WF;
    float* bf   = ws + OFF_BF;
    float* Wop  = ws + OFF_WOP;
    float* bop  = ws + OFF_BOP;
    float* xBCc = ws + OFF_XBC;
    float* dtv  = ws + OFF_DTV;
    float* dAv  = ws + OFF_DAV;
    float* ysb  = ws + OFF_YS;
    float* feat = ws + OFF_FEAT;
    float* agg  = ws + OFF_AGG;
    int*   slots = (int*)(ws + OFF_XBC);   // aliases xBCc (dead after k_scan)
    int*   cnt   = (int*)(ws + OFF_DTV);   // aliases dtv  (dead after k_scan)
    float* out  = (float*)d_out;

    hipMemsetAsync(feat, 0, (size_t)N_NODES_C * 16 * 4, stream);

    k_gather<<<(NROWS * 16 + 255) / 256, 256, 0, stream>>>(node_inputs, chk);
    k_fusew<<<(16 * DIP + DIP + DIN * 16 + 16 + 255) / 256, 256, 0, stream>>>(
        W_embed, b_embed, W_in, b_in, W_outp, b_outp, W_proj, b_proj, Wf, bf, Wop, bop);
    k_conv<<<dim3(2, 8, BATCH_C), 320, 0, stream>>>(chk, Wf, bf, conv_w, conv_b, xBCc);
    k_dt<<<(NROWS * NH + 255) / 256, 256, 0, stream>>>(chk, Wf, bf, A_log, dt_bias, dtv, dAv);
    k_scan<<<dim3(NH, BATCH_C), 256, 0, stream>>>(xBCc, dtv, dAv, D_skip, ysb);
    k_gate<<<NROWS, 256, 0, stream>>>(chk, Wf, bf, ysb, norm_w, Wop, bop, feat);
    // adjacency build (slots/cnt alias regions dead after k_scan)
    hipMemsetAsync(cnt, 0, (size_t)N_NODES_C * 4, stream);
    k_scatter<<<(N_EDGES_C + 255) / 256, 256, 0, stream>>>(src_ids, dst_ids, cnt, slots);
    k_agg<<<N_NODES_C, 128, 0, stream>>>(cnt, slots, feat, W_msg, b_msg, agg);
    k_upd2<<<N_NODES_C / UNB, 256, 0, stream>>>(feat, agg, W_upd, b_upd, W_out, b_out, out);
}

// Round 4
// 550.057 us; speedup vs baseline: 2.3002x; 1.2648x over previous
//
#include <hip/hip_runtime.h>
#include <math.h>

#define LSEQ 624
#define NPG_C 1249
#define BATCH_C 64
#define NROWS (BATCH_C*LSEQ)          // 39936
#define N_NODES_C 79936
#define N_EDGES_C 639488
#define DIP 1160
#define DIN 512
#define CDIM 640
#define NH 8
#define HD 64
#define DS 64
#define CAP 96
#define TCH 48
#define NCHK 13

// workspace layout (float offsets)
#define OFF_CHK   0            // 39936*16 = 638976
#define OFF_WF    638976       // 16*1160 = 18560
#define OFF_BF    657536       // 1160
#define OFF_WOP   658944       // 512*16 = 8192
#define OFF_BOP   667136       // 16
#define OFF_XBC   667392       // 39936*640 = 25559040  (reused as slots after k_carry)
#define OFF_DTV   26226432     // 39936*8              (reused as cnt after k_carry)
#define OFF_EV    26545920     // 39936*8  (log-dA per row/head)
#define OFF_YS    26865408     // 39936*512 = 20447232
#define OFF_FEAT  47312640     // 79936*16 = 1278976
#define OFF_AGG   48591616     // 79936*128 = 10231808 (Gm aliased here until k_agg)
// total 58823424 floats = 235.3 MB

__device__ __forceinline__ float siluf(float x) {
    return x / (1.f + __expf(-x));
}

// gather check-node rows
__global__ void k_gather(const float* __restrict__ ni, float* __restrict__ chk) {
    int gid = blockIdx.x * 256 + threadIdx.x;
    if (gid >= NROWS * 16) return;
    int row = gid >> 4, k = gid & 15;
    int node = (row / LSEQ) * NPG_C + (row % LSEQ);
    chk[gid] = ni[node * 16 + k];
}

// fused weights
__global__ void k_fusew(const float* __restrict__ We, const float* __restrict__ be,
                        const float* __restrict__ Wi, const float* __restrict__ bi,
                        const float* __restrict__ Wo, const float* __restrict__ bo,
                        const float* __restrict__ Wp, const float* __restrict__ bp,
                        float* __restrict__ Wf, float* __restrict__ bf,
                        float* __restrict__ Wop, float* __restrict__ bop) {
    int id = blockIdx.x * 256 + threadIdx.x;
    if (id < 16 * DIP) {
        int i = id / DIP, j = id % DIP;
        float s = 0.f;
        for (int k = 0; k < 256; k++) s = fmaf(We[i * 256 + k], Wi[k * DIP + j], s);
        Wf[id] = s;
    } else if (id < 16 * DIP + DIP) {
        int j = id - 16 * DIP;
        float s = bi[j];
        for (int k = 0; k < 256; k++) s = fmaf(be[k], Wi[k * DIP + j], s);
        bf[j] = s;
    } else if (id < 16 * DIP + DIP + DIN * 16) {
        int id2 = id - (16 * DIP + DIP);
        int c = id2 >> 4, o = id2 & 15;
        float s = 0.f;
        for (int k = 0; k < 256; k++) s = fmaf(Wo[c * 256 + k], Wp[k * 16 + o], s);
        Wop[id2] = s;
    } else if (id < 16 * DIP + DIP + DIN * 16 + 16) {
        int o = id - (16 * DIP + DIP + DIN * 16);
        float s = bp[o];
        for (int k = 0; k < 256; k++) s = fmaf(bo[k], Wp[k * 16 + o], s);
        bop[o] = s;
    }
}

// fused in_proj(xBC cols) + causal depthwise conv + silu
__global__ __launch_bounds__(320) void k_conv(const float* __restrict__ chk,
        const float* __restrict__ Wf, const float* __restrict__ bf,
        const float* __restrict__ cw, const float* __restrict__ cb,
        float* __restrict__ xBCc) {
    int c = blockIdx.x * 320 + threadIdx.x;     // 0..639
    int t0 = blockIdx.y * 78;
    int b = blockIdx.z;
    float w[16];
#pragma unroll
    for (int k = 0; k < 16; k++) w[k] = Wf[k * DIP + DIN + c];
    float bfx = bf[DIN + c];
    float k0 = cw[c * 4 + 0], k1 = cw[c * 4 + 1], k2 = cw[c * 4 + 2], k3 = cw[c * 4 + 3];
    float cbv = cb[c];
    const float* crow = chk + (size_t)(b * LSEQ) * 16;
    float* out = xBCc + (size_t)(b * LSEQ) * CDIM + c;

    float w0 = 0.f, w1 = 0.f, w2 = 0.f;
#pragma unroll
    for (int d = 3; d >= 1; d--) {
        int tau = t0 - d;
        float s = 0.f;
        if (tau >= 0) {
            s = bfx;
            const float* cr = crow + tau * 16;
#pragma unroll
            for (int k = 0; k < 16; k++) s = fmaf(cr[k], w[k], s);
        }
        if (d == 3) w0 = s; else if (d == 2) w1 = s; else w2 = s;
    }
    for (int t = t0; t < t0 + 78; t++) {
        const float* cr = crow + t * 16;
        float w3 = bfx;
#pragma unroll
        for (int k = 0; k < 16; k++) w3 = fmaf(cr[k], w[k], w3);
        float a = fmaf(k0, w0, fmaf(k1, w1, fmaf(k2, w2, fmaf(k3, w3, cbv))));
        out[(size_t)t * CDIM] = siluf(a);
        w0 = w1; w1 = w2; w2 = w3;
    }
}

// dt head columns: dtv = softplus(...), ev = -exp(A_log)*dtv  (= log dA)
__global__ void k_dt(const float* __restrict__ chk, const float* __restrict__ Wf,
                     const float* __restrict__ bf, const float* __restrict__ A_log,
                     const float* __restrict__ dt_bias,
                     float* __restrict__ dtv, float* __restrict__ ev) {
    int id = blockIdx.x * 256 + threadIdx.x;
    if (id >= NROWS * NH) return;
    int row = id >> 3, h = id & 7;
    const float* cr = chk + (size_t)row * 16;
    float s = bf[DIN + CDIM + h];
#pragma unroll
    for (int k = 0; k < 16; k++) s = fmaf(cr[k], Wf[k * DIP + DIN + CDIM + h], s);
    s += dt_bias[h];
    float sp = (s > 20.f) ? s : log1pf(__expf(s));
    dtv[id] = sp;
    ev[id] = -__expf(A_log[h]) * sp;
}

// G[t][s] = C_t . B_s per (b,chunk).  grid (13, 64), 256 thr.
__global__ __launch_bounds__(256) void k_gmat(const float* __restrict__ xBCc,
        float* __restrict__ Gm) {
    int c = blockIdx.x, b = blockIdx.y;
    int tid = threadIdx.x;
    int bs = b * LSEQ;
    __shared__ __align__(16) float sBC[TCH * 132];   // [t][0..63]=B, [t][64..127]=C
#pragma unroll
    for (int j = 0; j < 6; j++) {
        int g = j * 256 + tid;
        int f = g * 4;
        int t = f >> 7, col = f & 127;
        float4 v = *(const float4*)(xBCc + (size_t)(bs + c * TCH + t) * CDIM + 512 + col);
        *(float4*)&sBC[t * 132 + col] = v;
    }
    __syncthreads();
    int t0 = (tid >> 4) * 3, s0 = (tid & 15) * 3;
    float acc[3][3];
#pragma unroll
    for (int i = 0; i < 3; i++)
#pragma unroll
        for (int j = 0; j < 3; j++) acc[i][j] = 0.f;
    for (int k = 0; k < 64; k++) {
        float c0 = sBC[(t0 + 0) * 132 + 64 + k];
        float c1 = sBC[(t0 + 1) * 132 + 64 + k];
        float c2 = sBC[(t0 + 2) * 132 + 64 + k];
        float b0 = sBC[(s0 + 0) * 132 + k];
        float b1 = sBC[(s0 + 1) * 132 + k];
        float b2 = sBC[(s0 + 2) * 132 + k];
        acc[0][0] = fmaf(c0, b0, acc[0][0]); acc[0][1] = fmaf(c0, b1, acc[0][1]); acc[0][2] = fmaf(c0, b2, acc[0][2]);
        acc[1][0] = fmaf(c1, b0, acc[1][0]); acc[1][1] = fmaf(c1, b1, acc[1][1]); acc[1][2] = fmaf(c1, b2, acc[1][2]);
        acc[2][0] = fmaf(c2, b0, acc[2][0]); acc[2][1] = fmaf(c2, b1, acc[2][1]); acc[2][2] = fmaf(c2, b2, acc[2][2]);
    }
    size_t gb = (size_t)(b * NCHK + c) * (TCH * TCH);
#pragma unroll
    for (int i = 0; i < 3; i++)
#pragma unroll
        for (int j = 0; j < 3; j++)
            Gm[gb + (t0 + i) * TCH + (s0 + j)] = acc[i][j];
}

// intra-chunk: Y = M @ X + dsk*X, M[t][s] = exp(E[t]-E[s])*dt_s*G[t][s] (s<=t)
// grid (13, 8, 64) = (chunk, head, b), 256 thr
__global__ __launch_bounds__(256) void k_intra(const float* __restrict__ xBCc,
        const float* __restrict__ Gm, const float* __restrict__ dtv,
        const float* __restrict__ ev, const float* __restrict__ Dskip,
        float* __restrict__ ysb) {
    int c = blockIdx.x, head = blockIdx.y, b = blockIdx.z;
    int tid = threadIdx.x;
    int bs = b * LSEQ;
    int r0 = bs + c * TCH;
    __shared__ __align__(16) float sX[TCH * 64];
    __shared__ float sM[TCH * TCH];
    __shared__ float sEr[TCH], sE[TCH], sdt[TCH];

#pragma unroll
    for (int j = 0; j < 3; j++) {
        int g = j * 256 + tid;
        int f = g * 4;
        int t = f >> 6, col = f & 63;
        float4 v = *(const float4*)(xBCc + (size_t)(r0 + t) * CDIM + head * HD + col);
        *(float4*)&sX[t * 64 + col] = v;
    }
    if (tid < TCH) {
        sEr[tid] = ev[(size_t)(r0 + tid) * NH + head];
        sdt[tid] = dtv[(size_t)(r0 + tid) * NH + head];
    }
    __syncthreads();
    if (tid == 0) {
        float run = 0.f;
        for (int t = 0; t < TCH; t++) { run += sEr[t]; sE[t] = run; }
    }
    __syncthreads();
    size_t gb = (size_t)(b * NCHK + c) * (TCH * TCH);
#pragma unroll
    for (int k = 0; k < 9; k++) {
        int id = k * 256 + tid;
        int t = id / TCH, s = id - t * TCH;
        float g = Gm[gb + id];
        sM[id] = (s <= t) ? __expf(sE[t] - sE[s]) * sdt[s] * g : 0.f;
    }
    __syncthreads();

    int t0 = (tid >> 4) * 3, p4 = (tid & 15) * 4;
    float4 a0 = {0,0,0,0}, a1 = {0,0,0,0}, a2 = {0,0,0,0};
    for (int s = 0; s < TCH; s++) {
        float m0 = sM[(t0 + 0) * TCH + s];
        float m1 = sM[(t0 + 1) * TCH + s];
        float m2 = sM[(t0 + 2) * TCH + s];
        float4 xv = *(const float4*)&sX[s * 64 + p4];
        a0.x = fmaf(m0, xv.x, a0.x); a0.y = fmaf(m0, xv.y, a0.y);
        a0.z = fmaf(m0, xv.z, a0.z); a0.w = fmaf(m0, xv.w, a0.w);
        a1.x = fmaf(m1, xv.x, a1.x); a1.y = fmaf(m1, xv.y, a1.y);
        a1.z = fmaf(m1, xv.z, a1.z); a1.w = fmaf(m1, xv.w, a1.w);
        a2.x = fmaf(m2, xv.x, a2.x); a2.y = fmaf(m2, xv.y, a2.y);
        a2.z = fmaf(m2, xv.z, a2.z); a2.w = fmaf(m2, xv.w, a2.w);
    }
    float dsk = Dskip[head];
    float4 accs[3] = {a0, a1, a2};
#pragma unroll
    for (int i = 0; i < 3; i++) {
        float4 xo = *(const float4*)&sX[(t0 + i) * 64 + p4];
        float4 o;
        o.x = fmaf(dsk, xo.x, accs[i].x);
        o.y = fmaf(dsk, xo.y, accs[i].y);
        o.z = fmaf(dsk, xo.z, accs[i].z);
        o.w = fmaf(dsk, xo.w, accs[i].w);
        *(float4*)&ysb[(size_t)(r0 + t0 + i) * DIN + head * HD + p4] = o;
    }
}

// inter-chunk carry + y-correction: per (head,b): sequential over 13 chunks.
// h[p][n] per thread: 4p x 4n.  y_corr[t][p] = exp(E[t]) * sum_n C_t[n] h[p][n]
// grid (8, 64), 256 thr
__global__ __launch_bounds__(256) void k_carry(const float* __restrict__ xBCc,
        const float* __restrict__ dtv, const float* __restrict__ ev,
        float* __restrict__ ysb) {
    int head = blockIdx.x, b = blockIdx.y;
    int tid = threadIdx.x;
    int bs = b * LSEQ;
    __shared__ __align__(16) float sX[TCH * 64];
    __shared__ __align__(16) float sB[TCH * 64];
    __shared__ __align__(16) float sC[TCH * 68];
    __shared__ __align__(16) float hbuf[64 * 68];
    __shared__ float sEr[TCH], sE[TCH], sdt[TCH], wbuf[TCH], sDt[TCH];

    int i4 = (tid >> 4) * 4;   // p for state
    int j4 = (tid & 15) * 4;   // n for state
    int t0 = (tid >> 4) * 3;   // t for y-GEMM
    int p4 = (tid & 15) * 4;   // p for y-GEMM

    float h[4][4];
#pragma unroll
    for (int i = 0; i < 4; i++)
#pragma unroll
        for (int j = 0; j < 4; j++) h[i][j] = 0.f;

    for (int c = 0; c < NCHK; c++) {
        int r0 = bs + c * TCH;
        __syncthreads();   // protect LDS reuse across iterations
#pragma unroll
        for (int j = 0; j < 3; j++) {
            int g = j * 256 + tid;
            int f = g * 4;
            int t = f >> 6, col = f & 63;
            *(float4*)&sX[t * 64 + col] =
                *(const float4*)(xBCc + (size_t)(r0 + t) * CDIM + head * HD + col);
            *(float4*)&sB[t * 64 + col] =
                *(const float4*)(xBCc + (size_t)(r0 + t) * CDIM + 512 + col);
            *(float4*)&sC[t * 68 + col] =
                *(const float4*)(xBCc + (size_t)(r0 + t) * CDIM + 576 + col);
        }
        if (tid < TCH) {
            sEr[tid] = ev[(size_t)(r0 + tid) * NH + head];
            sdt[tid] = dtv[(size_t)(r0 + tid) * NH + head];
        }
        __syncthreads();
        if (tid == 0) {
            float run = 0.f;
            for (int t = 0; t < TCH; t++) { run += sEr[t]; sE[t] = run; }
        }
        __syncthreads();
        if (tid < TCH) {
            wbuf[tid] = __expf(sE[TCH - 1] - sE[tid]) * sdt[tid];
            sDt[tid] = __expf(sE[tid]);
        }
        // publish h_start to LDS for the y-GEMM
#pragma unroll
        for (int jj = 0; jj < 4; jj++) {
            float4 v = { h[0][jj], h[1][jj], h[2][jj], h[3][jj] };
            *(float4*)&hbuf[(j4 + jj) * 68 + i4] = v;
        }
        __syncthreads();

        if (c > 0) {
            float4 a0 = {0,0,0,0}, a1 = {0,0,0,0}, a2 = {0,0,0,0};
            for (int k = 0; k < 64; k++) {
                float c0 = sC[(t0 + 0) * 68 + k];
                float c1 = sC[(t0 + 1) * 68 + k];
                float c2 = sC[(t0 + 2) * 68 + k];
                float4 hv = *(const float4*)&hbuf[k * 68 + p4];
                a0.x = fmaf(c0, hv.x, a0.x); a0.y = fmaf(c0, hv.y, a0.y);
                a0.z = fmaf(c0, hv.z, a0.z); a0.w = fmaf(c0, hv.w, a0.w);
                a1.x = fmaf(c1, hv.x, a1.x); a1.y = fmaf(c1, hv.y, a1.y);
                a1.z = fmaf(c1, hv.z, a1.z); a1.w = fmaf(c1, hv.w, a1.w);
                a2.x = fmaf(c2, hv.x, a2.x); a2.y = fmaf(c2, hv.y, a2.y);
                a2.z = fmaf(c2, hv.z, a2.z); a2.w = fmaf(c2, hv.w, a2.w);
            }
            float4 accs[3] = {a0, a1, a2};
#pragma unroll
            for (int i = 0; i < 3; i++) {
                float d = sDt[t0 + i];
                float* yp = ysb + (size_t)(r0 + t0 + i) * DIN + head * HD + p4;
                float4 y = *(const float4*)yp;
                y.x = fmaf(d, accs[i].x, y.x);
                y.y = fmaf(d, accs[i].y, y.y);
                y.z = fmaf(d, accs[i].z, y.z);
                y.w = fmaf(d, accs[i].w, y.w);
                *(float4*)yp = y;
            }
        }

        // state update: h = exp(Elast)*h + sum_s wbuf[s] * X[s][p] * B[s][n]
        float eL = sDt[TCH - 1];
#pragma unroll
        for (int i = 0; i < 4; i++)
#pragma unroll
            for (int j = 0; j < 4; j++) h[i][j] *= eL;
        for (int s = 0; s < TCH; s++) {
            float w = wbuf[s];
            float4 xv = *(const float4*)&sX[s * 64 + i4];
            float4 bv = *(const float4*)&sB[s * 64 + j4];
            float x0 = w * xv.x, x1 = w * xv.y, x2 = w * xv.z, x3 = w * xv.w;
            h[0][0] = fmaf(x0, bv.x, h[0][0]); h[0][1] = fmaf(x0, bv.y, h[0][1]);
            h[0][2] = fmaf(x0, bv.z, h[0][2]); h[0][3] = fmaf(x0, bv.w, h[0][3]);
            h[1][0] = fmaf(x1, bv.x, h[1][0]); h[1][1] = fmaf(x1, bv.y, h[1][1]);
            h[1][2] = fmaf(x1, bv.z, h[1][2]); h[1][3] = fmaf(x1, bv.w, h[1][3]);
            h[2][0] = fmaf(x2, bv.x, h[2][0]); h[2][1] = fmaf(x2, bv.y, h[2][1]);
            h[2][2] = fmaf(x2, bv.z, h[2][2]); h[2][3] = fmaf(x2, bv.w, h[2][3]);
            h[3][0] = fmaf(x3, bv.x, h[3][0]); h[3][1] = fmaf(x3, bv.y, h[3][1]);
            h[3][2] = fmaf(x3, bv.z, h[3][2]); h[3][3] = fmaf(x3, bv.w, h[3][3]);
        }
    }
}

// gate (recompute z) + RMSNorm + fused out_proj@proj + scatter into feat
__global__ __launch_bounds__(256) void k_gate(const float* __restrict__ chk,
        const float* __restrict__ Wf, const float* __restrict__ bf,
        const float* __restrict__ ysb, const float* __restrict__ norm_w,
        const float* __restrict__ Wop, const float* __restrict__ bop,
        float* __restrict__ feat) {
    int row = blockIdx.x;
    int tid = threadIdx.x;
    int b = row / LSEQ, t = row % LSEQ;
    int node = b * NPG_C + t;
    __shared__ float sy[512];
    __shared__ float sred[256];
    __shared__ float swave[4];

    float cv[16];
    const float* cr = chk + (size_t)row * 16;
#pragma unroll
    for (int k = 0; k < 16; k++) cv[k] = cr[k];
    int c1 = tid, c2 = tid + 256;
    float z1 = bf[c1], z2 = bf[c2];
#pragma unroll
    for (int k = 0; k < 16; k++) {
        z1 = fmaf(cv[k], Wf[k * DIP + c1], z1);
        z2 = fmaf(cv[k], Wf[k * DIP + c2], z2);
    }
    float y1 = ysb[(size_t)row * DIN + c1] * siluf(z1);
    float y2 = ysb[(size_t)row * DIN + c2] * siluf(z2);
    float ss = y1 * y1 + y2 * y2;
#pragma unroll
    for (int off = 32; off >= 1; off >>= 1) ss += __shfl_xor(ss, off);
    int wid = tid >> 6, lane = tid & 63;
    if (lane == 0) swave[wid] = ss;
    __syncthreads();
    float tot = swave[0] + swave[1] + swave[2] + swave[3];
    float scale = 1.f / sqrtf(tot * (1.f / 512.f) + 1e-5f);
    sy[c1] = y1 * scale * norm_w[c1];
    sy[c2] = y2 * scale * norm_w[c2];
    __syncthreads();
    int o = tid & 15, kg = tid >> 4;
    float ps = 0.f;
#pragma unroll
    for (int j = 0; j < 32; j++) {
        int k = kg * 32 + j;
        ps = fmaf(sy[k], Wop[k * 16 + o], ps);
    }
    sred[kg * 16 + o] = ps;
    __syncthreads();
    if (tid < 16) {
        float s = bop[tid];
#pragma unroll
        for (int g = 0; g < 16; g++) s += sred[g * 16 + tid];
        feat[(size_t)node * 16 + tid] = s;
    }
}

// build per-dst adjacency: cnt (int) + slot list of src ids
__global__ void k_scatter(const int* __restrict__ src, const int* __restrict__ dst,
                          int* __restrict__ cnt, int* __restrict__ slots) {
    int e = blockIdx.x * 256 + threadIdx.x;
    if (e >= N_EDGES_C) return;
    int d = dst[e];
    int pos = atomicAdd(&cnt[d], 1);
    if (pos < CAP) slots[(size_t)d * CAP + pos] = src[e];
}

// dst-centric aggregate: block per node, thread per channel
__global__ __launch_bounds__(128) void k_agg(const int* __restrict__ cnt,
        const int* __restrict__ slots, const float* __restrict__ feat,
        const float* __restrict__ Wm, const float* __restrict__ bm,
        float* __restrict__ agg) {
    int d = blockIdx.x, c = threadIdx.x;
    int deg = cnt[d];
    if (deg > CAP) deg = CAP;
    float w[16];
#pragma unroll
    for (int k = 0; k < 16; k++) w[k] = Wm[k * 128 + c];
    float bmv = bm[c];
    float acc = 0.f;
    const int* sl = slots + (size_t)d * CAP;
    for (int e = 0; e < deg; e++) {
        int s = __builtin_amdgcn_readfirstlane(sl[e]);
        const float4* fr = (const float4*)(feat + (size_t)s * 16);
        float4 f0 = fr[0], f1 = fr[1], f2 = fr[2], f3 = fr[3];
        float m = bmv;
        m = fmaf(f0.x, w[0],  m); m = fmaf(f0.y, w[1],  m);
        m = fmaf(f0.z, w[2],  m); m = fmaf(f0.w, w[3],  m);
        m = fmaf(f1.x, w[4],  m); m = fmaf(f1.y, w[5],  m);
        m = fmaf(f1.z, w[6],  m); m = fmaf(f1.w, w[7],  m);
        m = fmaf(f2.x, w[8],  m); m = fmaf(f2.y, w[9],  m);
        m = fmaf(f2.z, w[10], m); m = fmaf(f2.w, w[11], m);
        m = fmaf(f3.x, w[12], m); m = fmaf(f3.y, w[13], m);
        m = fmaf(f3.z, w[14], m); m = fmaf(f3.w, w[15], m);
        acc += fmaxf(m, 0.f);
    }
    agg[(size_t)d * 128 + c] = acc;
}

// node update MLP + output head, 16 nodes per block
#define UNB 16
__global__ __launch_bounds__(256) void k_upd2(const float* __restrict__ feat,
        const float* __restrict__ agg, const float* __restrict__ Wu,
        const float* __restrict__ bu, const float* __restrict__ Wo2,
        const float* __restrict__ bo2, float* __restrict__ out) {
    int g0 = blockIdx.x * UNB;
    int tid = threadIdx.x;
    __shared__ __align__(16) float sin_[UNB][144];
    __shared__ float part[4][8][2];
    for (int w = tid; w < UNB * 144; w += 256) {
        int node = w / 144, k = w - node * 144;
        sin_[node][k] = (k < 16) ? feat[(size_t)(g0 + node) * 16 + k]
                                 : agg[(size_t)(g0 + node) * 128 + (k - 16)];
    }
    __syncthreads();
    int rr = tid >> 7, c = tid & 127;
    float acc[8];
#pragma unroll
    for (int nn = 0; nn < 8; nn++) acc[nn] = 0.f;
    for (int k0 = 0; k0 < 144; k0 += 4) {
        float wu0 = Wu[(k0 + 0) * 128 + c];
        float wu1 = Wu[(k0 + 1) * 128 + c];
        float wu2 = Wu[(k0 + 2) * 128 + c];
        float wu3 = Wu[(k0 + 3) * 128 + c];
#pragma unroll
        for (int nn = 0; nn < 8; nn++) {
            float4 s4 = *(const float4*)&sin_[rr * 8 + nn][k0];
            acc[nn] = fmaf(s4.x, wu0, acc[nn]);
            acc[nn] = fmaf(s4.y, wu1, acc[nn]);
            acc[nn] = fmaf(s4.z, wu2, acc[nn]);
            acc[nn] = fmaf(s4.w, wu3, acc[nn]);
        }
    }
    float buc = bu[c];
    float w0 = Wo2[c * 2], w1 = Wo2[c * 2 + 1];
    float p[8][2];
#pragma unroll
    for (int nn = 0; nn < 8; nn++) {
        float h = fmaxf(acc[nn] + buc, 0.f);
        p[nn][0] = h * w0;
        p[nn][1] = h * w1;
    }
#pragma unroll
    for (int off = 1; off < 64; off <<= 1) {
#pragma unroll
        for (int nn = 0; nn < 8; nn++) {
            p[nn][0] += __shfl_xor(p[nn][0], off);
            p[nn][1] += __shfl_xor(p[nn][1], off);
        }
    }
    int wv = tid >> 6;
    if ((tid & 63) == 0) {
#pragma unroll
        for (int nn = 0; nn < 8; nn++) {
            part[wv][nn][0] = p[nn][0];
            part[wv][nn][1] = p[nn][1];
        }
    }
    __syncthreads();
    if (tid < 32) {
        int o = tid & 1, nn = (tid >> 1) & 7, r2 = tid >> 4;
        float v = part[r2 * 2 + 0][nn][o] + part[r2 * 2 + 1][nn][o] + bo2[o];
        out[(size_t)(g0 + r2 * 8 + nn) * 2 + o] = v;
    }
}

extern "C" void kernel_launch(void* const* d_in, const int* in_sizes, int n_in,
                              void* d_out, int out_size, void* d_ws, size_t ws_size,
                              hipStream_t stream) {
    const float* node_inputs = (const float*)d_in[0];
    const int*   src_ids     = (const int*)d_in[1];
    const int*   dst_ids     = (const int*)d_in[2];
    const float* W_embed     = (const float*)d_in[3];
    const float* b_embed     = (const float*)d_in[4];
    const float* W_in        = (const float*)d_in[5];
    const float* b_in        = (const float*)d_in[6];
    const float* conv_w      = (const float*)d_in[7];
    const float* conv_b      = (const float*)d_in[8];
    const float* A_log       = (const float*)d_in[9];
    const float* dt_bias     = (const float*)d_in[10];
    const float* D_skip      = (const float*)d_in[11];
    const float* norm_w      = (const float*)d_in[12];
    const float* W_outp      = (const float*)d_in[13];
    const float* b_outp      = (const float*)d_in[14];
    const float* W_proj      = (const float*)d_in[15];
    const float* b_proj      = (const float*)d_in[16];
    const float* W_msg       = (const float*)d_in[17];
    const float* b_msg       = (const float*)d_in[18];
    const float* W_upd       = (const float*)d_in[19];
    const float* b_upd       = (const float*)d_in[20];
    const float* W_out       = (const float*)d_in[21];
    const float* b_out       = (const float*)d_in[22];

    float* ws   = (float*)d_ws;
    float* chk  = ws + OFF_CHK;
    float* Wf   = ws + OFF_WF;
    float* bf   = ws + OFF_BF;
    float* Wop  = ws + OFF_WOP;
    float* bop  = ws + OFF_BOP;
    float* xBCc = ws + OFF_XBC;
    float* dtv  = ws + OFF_DTV;
    float* ev   = ws + OFF_EV;
    float* ysb  = ws + OFF_YS;
    float* feat = ws + OFF_FEAT;
    float* agg  = ws + OFF_AGG;
    float* Gm   = ws + OFF_AGG;            // aliases agg (dead until k_agg)
    int*   slots = (int*)(ws + OFF_XBC);   // aliases xBCc (dead after k_carry)
    int*   cnt   = (int*)(ws + OFF_DTV);   // aliases dtv  (dead after k_carry)
    float* out  = (float*)d_out;

    hipMemsetAsync(feat, 0, (size_t)N_NODES_C * 16 * 4, stream);

    k_gather<<<(NROWS * 16 + 255) / 256, 256, 0, stream>>>(node_inputs, chk);
    k_fusew<<<(16 * DIP + DIP + DIN * 16 + 16 + 255) / 256, 256, 0, stream>>>(
        W_embed, b_embed, W_in, b_in, W_outp, b_outp, W_proj, b_proj, Wf, bf, Wop, bop);
    k_conv<<<dim3(2, 8, BATCH_C), 320, 0, stream>>>(chk, Wf, bf, conv_w, conv_b, xBCc);
    k_dt<<<(NROWS * NH + 255) / 256, 256, 0, stream>>>(chk, Wf, bf, A_log, dt_bias, dtv, ev);
    k_gmat<<<dim3(NCHK, BATCH_C), 256, 0, stream>>>(xBCc, Gm);
    k_intra<<<dim3(NCHK, NH, BATCH_C), 256, 0, stream>>>(xBCc, Gm, dtv, ev, D_skip, ysb);
    k_carry<<<dim3(NH, BATCH_C), 256, 0, stream>>>(xBCc, dtv, ev, ysb);
    k_gate<<<NROWS, 256, 0, stream>>>(chk, Wf, bf, ysb, norm_w, Wop, bop, feat);
    // adjacency build (slots/cnt alias regions dead after k_carry)
    hipMemsetAsync(cnt, 0, (size_t)N_NODES_C * 4, stream);
    k_scatter<<<(N_EDGES_C + 255) / 256, 256, 0, stream>>>(src_ids, dst_ids, cnt, slots);
    k_agg<<<N_NODES_C, 128, 0, stream>>>(cnt, slots, feat, W_msg, b_msg, agg);
    k_upd2<<<N_NODES_C / UNB, 256, 0, stream>>>(feat, agg, W_upd, b_upd, W_out, b_out, out);
}